// Round 8
// baseline (1186.352 us; speedup 1.0000x reference)
//
#include <hip/hip_runtime.h>
#include <hip/hip_bf16.h>
#include <math.h>

#define NNODES 50000
#define NPAD   50176              // 392*128, padded rows for MFMA tile overrun
#define NEDGES 800000
#define NHOPS  4
#define NF     256
#define NH     128
#define NO     64

#define CONVX_BLOCKS 12500        // NNODES*NF/4/256
#define CONVW_BLOCKS 512          // NHOPS*NH*NF/256
#define LIN_PER_HOP  391          // ceil(NNODES/128)
#define LIN_BLOCKS   (LIN_PER_HOP * NHOPS)     // 1564

#define NBUCK 782                 // buckets of 64 rows: ceil(50000/64)
#define BCAP  1536                // mean 1024 + 16 sigma; overflow P ~ 1e-37

typedef __attribute__((ext_vector_type(8))) short bfrag_t;   // 8 x bf16
typedef __attribute__((ext_vector_type(4))) float facc_t;    // 4 x f32
typedef unsigned long long ull_t;

static __device__ __forceinline__ unsigned short f2bf(float f) {
  unsigned int u = __float_as_uint(f);
  unsigned int r = (u + 0x7fffu + ((u >> 16) & 1u)) >> 16;
  return (unsigned short)r;
}
static __device__ __forceinline__ float bf2f_lo(unsigned int u) {
  return __uint_as_float(u << 16);
}
static __device__ __forceinline__ float bf2f_hi(unsigned int u) {
  return __uint_as_float(u & 0xffff0000u);
}

// ---------------------------------------------------------------------------
// Phase A (fused): convx | convw. (hist removed — per-row counts now come
// from pass2's LDS count+scan.)
// ---------------------------------------------------------------------------
__global__ __launch_bounds__(256) void phaseA_kernel(
    const float* __restrict__ x, unsigned short* __restrict__ xb,
    const float* __restrict__ W, unsigned short* __restrict__ Wt) {
  const int bx = blockIdx.x;
  const int t  = threadIdx.x;
  if (bx < CONVX_BLOCKS) {
    const size_t i = ((size_t)bx * 256 + t) * 4;
    float4 v = *(const float4*)&x[i];
    ushort4 o;
    o.x = f2bf(v.x); o.y = f2bf(v.y); o.z = f2bf(v.z); o.w = f2bf(v.w);
    *(ushort4*)&xb[i] = o;
  } else {
    const int i = (bx - CONVX_BLOCKS) * 256 + t;
    const int k = i / (NH * NF);
    const int rem = i - k * NH * NF;
    const int n = rem / NF;
    const int f = rem - n * NF;
    Wt[i] = f2bf(W[(size_t)k * NF * NH + (size_t)f * NH + n]);
  }
}

// ---------------------------------------------------------------------------
// Linear via MFMA, all 4 hops in one dispatch (1564 blocks).
// Block = 256 thr = 4 waves (2x2), each wave 64x64 via 4x4 16x16x32 tiles.
// ---------------------------------------------------------------------------
__global__ __launch_bounds__(256) void linear_kernel(
    const unsigned short* __restrict__ xb, const unsigned short* __restrict__ Wt,
    const float* __restrict__ b, unsigned short* __restrict__ slots) {
  const int lb  = blockIdx.x;
  const int hop = lb / LIN_PER_HOP;
  const int mb  = lb - hop * LIN_PER_HOP;
  const unsigned short* Wk = Wt + (size_t)hop * NH * NF;
  const float* bk = b + hop * NH;
  unsigned short* hb = slots + (size_t)(hop + 1) * NNODES * NH;

  const int t    = threadIdx.x;
  const int lane = t & 63;
  const int wave = t >> 6;
  const int wm   = (wave >> 1) * 64;
  const int wn   = (wave & 1) * 64;
  const int m0   = mb * 128;
  const int l15  = lane & 15;
  const int quad = lane >> 4;

  facc_t acc[4][4];
#pragma unroll
  for (int i = 0; i < 4; ++i)
#pragma unroll
    for (int j = 0; j < 4; ++j) {
      facc_t z = {0.f, 0.f, 0.f, 0.f};
      acc[i][j] = z;
    }

#pragma unroll
  for (int k0 = 0; k0 < NF; k0 += 32) {
    bfrag_t a[4], bb[4];
#pragma unroll
    for (int mi = 0; mi < 4; ++mi) {
      const int m = m0 + wm + mi * 16 + l15;
      a[mi] = *(const bfrag_t*)&xb[(size_t)m * NF + k0 + quad * 8];
    }
#pragma unroll
    for (int ni = 0; ni < 4; ++ni) {
      const int n = wn + ni * 16 + l15;
      bb[ni] = *(const bfrag_t*)&Wk[(size_t)n * NF + k0 + quad * 8];
    }
#pragma unroll
    for (int mi = 0; mi < 4; ++mi)
#pragma unroll
      for (int ni = 0; ni < 4; ++ni)
        acc[mi][ni] = __builtin_amdgcn_mfma_f32_16x16x32_bf16(
            a[mi], bb[ni], acc[mi][ni], 0, 0, 0);
  }

#pragma unroll
  for (int ni = 0; ni < 4; ++ni) {
    const int n = wn + ni * 16 + l15;
    const float bias = bk[n];
#pragma unroll
    for (int mi = 0; mi < 4; ++mi) {
#pragma unroll
      for (int r = 0; r < 4; ++r) {
        const int m = m0 + wm + mi * 16 + quad * 4 + r;
        if (m < NNODES) hb[(size_t)m * NH + n] = f2bf(acc[mi][ni][r] + bias);
      }
    }
  }
}

// ---------------------------------------------------------------------------
// CSR build pass 1: bin edges into 782 row-buckets (append atomics; stores
// target 782 hot tails instead of 25.6MB of random lines).
// Packed 8B: [val:32 | rlocal:6 | col:16]. grid = (3125, 2 hops).
// ---------------------------------------------------------------------------
__global__ __launch_bounds__(256) void pass1_kernel(
    const int* __restrict__ erows, const int* __restrict__ ecols,
    const float* __restrict__ evals, int* __restrict__ bcur,
    ull_t* __restrict__ tmp, int hop_base) {
  const int h  = blockIdx.y;                 // local hop 0..1
  const int gh = hop_base + h;
  const int e  = blockIdx.x * 256 + threadIdx.x;   // 0..799999 (exact)
  const size_t g = (size_t)gh * NEDGES + e;
  const int r = erows[g];
  const int b = r >> 6;
  const int pos = atomicAdd(&bcur[gh * NBUCK + b], 1);
  if (pos < BCAP) {
    const unsigned int lo =
        ((unsigned int)(r & 63) << 16) | (unsigned int)ecols[g];
    const ull_t pk = ((ull_t)__float_as_uint(evals[g]) << 32) | lo;
    tmp[((size_t)h * NBUCK + b) * BCAP + pos] = pk;
  }
}

// ---------------------------------------------------------------------------
// Bucket-base scan: exclusive scan of 782 bucket counts per hop.
// grid = 2 blocks (one per hop in batch) x 64 threads (one wave).
// Also writes offs[hop][NNODES] = total.
// ---------------------------------------------------------------------------
__global__ __launch_bounds__(64) void bscan_kernel(
    const int* __restrict__ bcur, int* __restrict__ bbase,
    int* __restrict__ offs, int hop_base) {
  const int gh   = hop_base + blockIdx.x;
  const int lane = threadIdx.x;
  int carry = 0;
  for (int c0 = 0; c0 < NBUCK; c0 += 64) {
    const int b = c0 + lane;
    int v = 0;
    if (b < NBUCK) {
      v = bcur[gh * NBUCK + b];
      v = v < BCAP ? v : BCAP;
    }
    int s = v;
#pragma unroll
    for (int d = 1; d < 64; d <<= 1) {
      int n = __shfl_up(s, d, 64);
      if (lane >= d) s += n;
    }
    if (b < NBUCK) bbase[gh * NBUCK + b] = carry + s - v;
    carry += __shfl(s, 63, 64);
  }
  if (lane == 0) offs[(size_t)gh * (NNODES + 1) + NNODES] = carry;
}

// ---------------------------------------------------------------------------
// CSR build pass 2: one block per bucket. Stage edges in LDS, count the 64
// local rows (LDS atomics), wave-scan -> per-row offs, place edges into the
// bucket's ~8KB contiguous ecsr window (single-block => full-line writes).
// grid = (782, 2 hops).
// ---------------------------------------------------------------------------
__global__ __launch_bounds__(256) void pass2_kernel(
    const int* __restrict__ bcur, const int* __restrict__ bbase,
    const ull_t* __restrict__ tmp, int* __restrict__ offs,
    ull_t* __restrict__ ecsr, int hop_base) {
  __shared__ ull_t est[BCAP];
  __shared__ int cnt[64];
  __shared__ int cur[64];
  const int h  = blockIdx.y;
  const int gh = hop_base + h;
  const int b  = blockIdx.x;
  const int t  = threadIdx.x;

  int nb = bcur[gh * NBUCK + b];
  nb = nb < BCAP ? nb : BCAP;
  const int base = bbase[gh * NBUCK + b];

  for (int i = t; i < nb; i += 256)
    est[i] = tmp[((size_t)h * NBUCK + b) * BCAP + i];
  if (t < 64) cnt[t] = 0;
  __syncthreads();

  for (int i = t; i < nb; i += 256) {
    const int rl = (int)(((unsigned int)est[i] >> 16) & 63u);
    atomicAdd(&cnt[rl], 1);
  }
  __syncthreads();

  if (t < 64) {
    const int v = cnt[t];
    int s = v;
#pragma unroll
    for (int d = 1; d < 64; d <<= 1) {
      int n = __shfl_up(s, d, 64);
      if (t >= d) s += n;
    }
    const int excl = s - v;
    cur[t] = excl;
    const int r = b * 64 + t;
    if (r < NNODES) offs[(size_t)gh * (NNODES + 1) + r] = base + excl;
  }
  __syncthreads();

  ull_t* dst = ecsr + (size_t)gh * NEDGES;
  for (int i = t; i < nb; i += 256) {
    const ull_t pk = est[i];
    const unsigned int lo = (unsigned int)pk;
    const int rl = (int)((lo >> 16) & 63u);
    const int pos = base + atomicAdd(&cur[rl], 1);
    dst[pos] = (pk & 0xffffffff00000000ull) | (ull_t)(lo & 0xffffu);
  }
}

// ---------------------------------------------------------------------------
// Gather SpMM (ONE HOP per dispatch — sequential dispatches enforce the
// hb[k]/agg[k] slot-aliasing dependency). 1 wave/row; wave = 4 edge-groups
// x 16 lanes x 16B; 16 edges in flight.
// ---------------------------------------------------------------------------
__global__ __launch_bounds__(256) void gather_kernel(
    const int* __restrict__ offs, const int2* __restrict__ ecsr,
    const unsigned short* __restrict__ hb, unsigned short* __restrict__ aggb) {
  const int t    = threadIdx.x;
  const int lane = t & 63;
  const int wid  = t >> 6;
  const int r = blockIdx.x * 4 + wid;
  const int g  = lane >> 4;    // edge subgroup 0..3
  const int sl = lane & 15;    // feature slice: feats sl*8 .. sl*8+7
  const int s = offs[r];
  const int e = offs[r + 1];

  float acc[8];
#pragma unroll
  for (int j = 0; j < 8; ++j) acc[j] = 0.f;

  for (int p = s; p < e; p += 16) {
    int2 ed[4];
#pragma unroll
    for (int q = 0; q < 4; ++q) {
      const int idx = p + q * 4 + g;
      ed[q] = (idx < e) ? ecsr[idx] : make_int2(0, 0);
    }
    uint4 hv[4];
#pragma unroll
    for (int q = 0; q < 4; ++q)
      hv[q] = *(const uint4*)&hb[(size_t)ed[q].x * NH + sl * 8];
#pragma unroll
    for (int q = 0; q < 4; ++q) {
      const float v = __int_as_float(ed[q].y);
      acc[0] += v * bf2f_lo(hv[q].x);
      acc[1] += v * bf2f_hi(hv[q].x);
      acc[2] += v * bf2f_lo(hv[q].y);
      acc[3] += v * bf2f_hi(hv[q].y);
      acc[4] += v * bf2f_lo(hv[q].z);
      acc[5] += v * bf2f_hi(hv[q].z);
      acc[6] += v * bf2f_lo(hv[q].w);
      acc[7] += v * bf2f_hi(hv[q].w);
    }
  }

#pragma unroll
  for (int j = 0; j < 8; ++j) {
    acc[j] += __shfl_xor(acc[j], 16, 64);
    acc[j] += __shfl_xor(acc[j], 32, 64);
  }

  if (g == 0) {
    uint4 o;
    o.x = (unsigned)f2bf(acc[0]) | ((unsigned)f2bf(acc[1]) << 16);
    o.y = (unsigned)f2bf(acc[2]) | ((unsigned)f2bf(acc[3]) << 16);
    o.z = (unsigned)f2bf(acc[4]) | ((unsigned)f2bf(acc[5]) << 16);
    o.w = (unsigned)f2bf(acc[6]) | ((unsigned)f2bf(acc[7]) << 16);
    *(uint4*)&aggb[(size_t)r * NH + sl * 8] = o;
  }
}

// ---------------------------------------------------------------------------
// Output: out[n][o] = b_out[o] + sum_f elu(concat[n][f]) * W_out[f][o]
// ---------------------------------------------------------------------------
__global__ __launch_bounds__(64) void out_kernel(
    const unsigned short* __restrict__ aggb, const float* __restrict__ Wout,
    const float* __restrict__ bout, float* __restrict__ out) {
  __shared__ float zs[16 * 516];
  const int t  = threadIdx.x;
  const int n0 = blockIdx.x * 16;

#pragma unroll
  for (int cch = 0; cch < 32; ++cch) {
    const int flat = cch * 256 + t * 4;
    const int n_l  = flat >> 9;
    const int f    = flat & 511;
    const int k    = f >> 7;
    const int j    = f & 127;
    const uint2 u = *(const uint2*)&aggb[((size_t)k * NNODES + n0 + n_l) * NH + j];
    float4 v = make_float4(bf2f_lo(u.x), bf2f_hi(u.x), bf2f_lo(u.y), bf2f_hi(u.y));
    v.x = v.x > 0.f ? v.x : (expf(v.x) - 1.f);
    v.y = v.y > 0.f ? v.y : (expf(v.y) - 1.f);
    v.z = v.z > 0.f ? v.z : (expf(v.z) - 1.f);
    v.w = v.w > 0.f ? v.w : (expf(v.w) - 1.f);
    *(float4*)&zs[n_l * 516 + f] = v;
  }
  __syncthreads();

  const int og = t & 15;
  const int ng = t >> 4;
  float acc[4][4];
#pragma unroll
  for (int i = 0; i < 4; ++i)
#pragma unroll
    for (int o = 0; o < 4; ++o) acc[i][o] = 0.f;

  for (int fq = 0; fq < 128; ++fq) {
    const int f = fq * 4;
    float4 z[4], w[4];
#pragma unroll
    for (int i = 0; i < 4; ++i)
      z[i] = *(float4*)&zs[(ng * 4 + i) * 516 + f];
#pragma unroll
    for (int u = 0; u < 4; ++u)
      w[u] = *(const float4*)&Wout[(size_t)(f + u) * NO + og * 4];
    float zv[4][4] = {{z[0].x, z[0].y, z[0].z, z[0].w},
                      {z[1].x, z[1].y, z[1].z, z[1].w},
                      {z[2].x, z[2].y, z[2].z, z[2].w},
                      {z[3].x, z[3].y, z[3].z, z[3].w}};
    float wv[4][4] = {{w[0].x, w[0].y, w[0].z, w[0].w},
                      {w[1].x, w[1].y, w[1].z, w[1].w},
                      {w[2].x, w[2].y, w[2].z, w[2].w},
                      {w[3].x, w[3].y, w[3].z, w[3].w}};
#pragma unroll
    for (int i = 0; i < 4; ++i)
#pragma unroll
      for (int u = 0; u < 4; ++u)
#pragma unroll
        for (int o = 0; o < 4; ++o) acc[i][o] += zv[i][u] * wv[u][o];
  }

  float bo[4];
#pragma unroll
  for (int o = 0; o < 4; ++o) bo[o] = bout[og * 4 + o];
#pragma unroll
  for (int i = 0; i < 4; ++i) {
    const int n = n0 + ng * 4 + i;
    float4 r = make_float4(acc[i][0] + bo[0], acc[i][1] + bo[1],
                           acc[i][2] + bo[2], acc[i][3] + bo[3]);
    *(float4*)&out[(size_t)n * NO + og * 4] = r;
  }
}

// ---------------------------------------------------------------------------
extern "C" void kernel_launch(void* const* d_in, const int* in_sizes, int n_in,
                              void* d_out, int out_size, void* d_ws, size_t ws_size,
                              hipStream_t stream) {
  const float* x     = (const float*)d_in[0];
  const float* W     = (const float*)d_in[1];
  const float* b     = (const float*)d_in[2];
  const float* W_out = (const float*)d_in[3];
  const float* b_out = (const float*)d_in[4];
  const int*   erows = (const int*)d_in[5];
  const int*   ecols = (const int*)d_in[6];
  const float* evals = (const float*)d_in[7];
  float* out = (float*)d_out;

  // ws layout (bytes), total ~116.4e6 (<118e6 known-good):
  //   slots: 5 x NNODES*NH bf16 = 64.0e6  (agg[k]=slot k, hb[k]=slot k+1;
  //          aliasing safe ONLY because gathers are sequential dispatches)
  //   xb: NPAD*NF bf16 = 25.69e6  (dead after linear; tmp [2x782x1536x8B
  //       = 19.2e6] aliases it during the two CSR-build batches)
  //   Wt: 0.26e6 | ecsr: 25.6e6 | offs 0.8e6 | bcur/bbase ~25e3
  unsigned short* slots = (unsigned short*)d_ws;
  unsigned short* xb = slots + (size_t)(NHOPS + 1) * NNODES * NH;
  unsigned short* Wt = xb + (size_t)NPAD * NF;
  ull_t* ecsr = (ull_t*)(Wt + (size_t)NHOPS * NH * NF);
  int* offs  = (int*)(ecsr + (size_t)NHOPS * NEDGES);
  int* bcur  = offs + NHOPS * (NNODES + 1);
  int* bbase = bcur + NHOPS * NBUCK;
  ull_t* tmp = (ull_t*)xb;   // aliases xb after linear

  hipMemsetAsync(bcur, 0, (size_t)NHOPS * NBUCK * sizeof(int), stream);

  phaseA_kernel<<<CONVX_BLOCKS + CONVW_BLOCKS, 256, 0, stream>>>(x, xb, W, Wt);
  linear_kernel<<<LIN_BLOCKS, 256, 0, stream>>>(xb, Wt, b, slots);

  for (int hb = 0; hb < NHOPS; hb += 2) {
    pass1_kernel<<<dim3(NEDGES / 256, 2), 256, 0, stream>>>(
        erows, ecols, evals, bcur, tmp, hb);
    bscan_kernel<<<2, 64, 0, stream>>>(bcur, bbase, offs, hb);
    pass2_kernel<<<dim3(NBUCK, 2), 256, 0, stream>>>(
        bcur, bbase, tmp, offs, ecsr, hb);
  }

  for (int k = 0; k < NHOPS; ++k) {
    gather_kernel<<<NNODES / 4, 256, 0, stream>>>(
        offs + (size_t)k * (NNODES + 1), (const int2*)(ecsr + (size_t)k * NEDGES),
        slots + (size_t)(k + 1) * NNODES * NH,   // hb[k]
        slots + (size_t)k * NNODES * NH);        // agg[k]
  }

  out_kernel<<<NNODES / 16, 64, 0, stream>>>(slots, W_out, b_out, out);
}

// Round 9
// 897.855 us; speedup vs baseline: 1.3213x; 1.3213x over previous
//
#include <hip/hip_runtime.h>
#include <hip/hip_bf16.h>
#include <math.h>

#define NNODES 50000
#define NPAD   50176              // 392*128, padded rows for MFMA tile overrun
#define NEDGES 800000
#define NHOPS  4
#define NF     256
#define NH     128
#define NO     64

#define CONVX_BLOCKS 12500        // NNODES*NF/4/256
#define CONVW_BLOCKS 512          // NHOPS*NH*NF/256
#define HIST_BLOCKS  12500        // (NEDGES/256)*NHOPS
#define LIN_PER_HOP  391          // ceil(NNODES/128)
#define LIN_BLOCKS   (LIN_PER_HOP * NHOPS)     // 1564
#define ZSTR 520                  // zs row stride in shorts (16B-aligned, bank-spread)

typedef __attribute__((ext_vector_type(8))) short bfrag_t;   // 8 x bf16
typedef __attribute__((ext_vector_type(4))) float facc_t;    // 4 x f32
typedef unsigned long long ull_t;

static __device__ __forceinline__ unsigned short f2bf(float f) {
  unsigned int u = __float_as_uint(f);
  unsigned int r = (u + 0x7fffu + ((u >> 16) & 1u)) >> 16;
  return (unsigned short)r;
}
static __device__ __forceinline__ float bf2f_lo(unsigned int u) {
  return __uint_as_float(u << 16);
}
static __device__ __forceinline__ float bf2f_hi(unsigned int u) {
  return __uint_as_float(u & 0xffff0000u);
}
static __device__ __forceinline__ float elu(float x) {
  return x > 0.f ? x : (expf(x) - 1.f);
}

// ---------------------------------------------------------------------------
// Phase A (fused): convx | convw | hist (per-row histogram; ~16 atomics per
// address — well under the ~32 same-address atomic serialization budget).
// ---------------------------------------------------------------------------
__global__ __launch_bounds__(256) void phaseA_kernel(
    const float* __restrict__ x, unsigned short* __restrict__ xb,
    const float* __restrict__ W, unsigned short* __restrict__ Wt,
    const int* __restrict__ erows, int* __restrict__ counts) {
  const int bx = blockIdx.x;
  const int t  = threadIdx.x;
  if (bx < CONVX_BLOCKS) {
    const size_t i = ((size_t)bx * 256 + t) * 4;
    float4 v = *(const float4*)&x[i];
    ushort4 o;
    o.x = f2bf(v.x); o.y = f2bf(v.y); o.z = f2bf(v.z); o.w = f2bf(v.w);
    *(ushort4*)&xb[i] = o;
  } else if (bx < CONVX_BLOCKS + CONVW_BLOCKS) {
    const int i = (bx - CONVX_BLOCKS) * 256 + t;
    const int k = i / (NH * NF);
    const int rem = i - k * NH * NF;
    const int n = rem / NF;
    const int f = rem - n * NF;
    Wt[i] = f2bf(W[(size_t)k * NF * NH + (size_t)f * NH + n]);
  } else {
    const int id  = bx - (CONVX_BLOCKS + CONVW_BLOCKS);
    const int hop = id / 3125;
    const int e   = (id - hop * 3125) * 256 + t;
    const int r = erows[(size_t)hop * NEDGES + e];
    atomicAdd(&counts[hop * NNODES + r], 1);
  }
}

// ---------------------------------------------------------------------------
// Exclusive scan per hop. 8 items/thread -> 7 chunk iters. Writes offs+cursor.
// ---------------------------------------------------------------------------
__global__ __launch_bounds__(1024) void scan_kernel(
    const int* __restrict__ counts, int* __restrict__ offs,
    int* __restrict__ cursor) {
  const int hop  = blockIdx.x;
  const int t    = threadIdx.x;
  const int lane = t & 63;
  const int wid  = t >> 6;
  __shared__ int wsum[16];
  __shared__ int carry_s;
  if (t == 0) carry_s = 0;
  __syncthreads();
  const int CH  = 8192;
  const int nch = (NNODES + CH - 1) / CH;     // 7
  for (int ch = 0; ch < nch; ++ch) {
    const int i0 = ch * CH + t * 8;
    int v[8];
    if (i0 + 7 < NNODES) {
      int4 a = *(const int4*)&counts[hop * NNODES + i0];
      int4 b = *(const int4*)&counts[hop * NNODES + i0 + 4];
      v[0]=a.x; v[1]=a.y; v[2]=a.z; v[3]=a.w;
      v[4]=b.x; v[5]=b.y; v[6]=b.z; v[7]=b.w;
    } else {
#pragma unroll
      for (int j = 0; j < 8; ++j)
        v[j] = (i0 + j < NNODES) ? counts[hop * NNODES + i0 + j] : 0;
    }
    int l[8];
    int run = 0;
#pragma unroll
    for (int j = 0; j < 8; ++j) { run += v[j]; l[j] = run; }
    int s = run;
#pragma unroll
    for (int d = 1; d < 64; d <<= 1) {
      int n = __shfl_up(s, d, 64);
      if (lane >= d) s += n;
    }
    if (lane == 63) wsum[wid] = s;
    __syncthreads();
    if (t < 16) {
      int ws = wsum[t];
#pragma unroll
      for (int d = 1; d < 16; d <<= 1) {
        int n = __shfl_up(ws, d, 16);
        if (t >= d) ws += n;
      }
      wsum[t] = ws;
    }
    __syncthreads();
    const int base = carry_s + (wid ? wsum[wid - 1] : 0) + (s - run);
    if (i0 + 7 < NNODES) {
      int4 o0 = make_int4(base, base + l[0], base + l[1], base + l[2]);
      int4 o1 = make_int4(base + l[3], base + l[4], base + l[5], base + l[6]);
      *(int4*)&offs[hop * (NNODES + 1) + i0]     = o0;
      *(int4*)&offs[hop * (NNODES + 1) + i0 + 4] = o1;
      *(int4*)&cursor[hop * NNODES + i0]     = o0;
      *(int4*)&cursor[hop * NNODES + i0 + 4] = o1;
    } else {
#pragma unroll
      for (int j = 0; j < 8; ++j) {
        if (i0 + j < NNODES) {
          const int excl = base + (l[j] - v[j]);
          offs[hop * (NNODES + 1) + i0 + j] = excl;
          cursor[hop * NNODES + i0 + j]     = excl;
        }
      }
    }
    __syncthreads();
    if (t == 0) carry_s += wsum[15];
    __syncthreads();
  }
  if (t == 0) offs[hop * (NNODES + 1) + NNODES] = carry_s;
}

// ---------------------------------------------------------------------------
// Linear via MFMA, all 4 hops (1564 blocks). Register-double-buffered K-loop:
// frags for k0+1 load during MFMAs of k0 (R8 finding: VGPR=68 => compiler
// does no lookahead; the 8 K-steps serialize on L2 latency).
// hb[k] = slots + k*NNODES*NH.
// ---------------------------------------------------------------------------
__global__ __launch_bounds__(256) void linear_kernel(
    const unsigned short* __restrict__ xb, const unsigned short* __restrict__ Wt,
    const float* __restrict__ b, unsigned short* __restrict__ slots) {
  const int lb  = blockIdx.x;
  const int hop = lb / LIN_PER_HOP;
  const int mb  = lb - hop * LIN_PER_HOP;
  const unsigned short* Wk = Wt + (size_t)hop * NH * NF;
  const float* bk = b + hop * NH;
  unsigned short* hb = slots + (size_t)hop * NNODES * NH;

  const int t    = threadIdx.x;
  const int lane = t & 63;
  const int wave = t >> 6;
  const int wm   = (wave >> 1) * 64;
  const int wn   = (wave & 1) * 64;
  const int m0   = mb * 128;
  const int l15  = lane & 15;
  const int quad = lane >> 4;

  facc_t acc[4][4];
#pragma unroll
  for (int i = 0; i < 4; ++i)
#pragma unroll
    for (int j = 0; j < 4; ++j) {
      facc_t z = {0.f, 0.f, 0.f, 0.f};
      acc[i][j] = z;
    }

  bfrag_t a[2][4], bb[2][4];
#pragma unroll
  for (int mi = 0; mi < 4; ++mi) {
    const int m = m0 + wm + mi * 16 + l15;
    a[0][mi] = *(const bfrag_t*)&xb[(size_t)m * NF + quad * 8];
  }
#pragma unroll
  for (int ni = 0; ni < 4; ++ni) {
    const int n = wn + ni * 16 + l15;
    bb[0][ni] = *(const bfrag_t*)&Wk[(size_t)n * NF + quad * 8];
  }

#pragma unroll
  for (int kk = 0; kk < 8; ++kk) {
    const int cur = kk & 1;
    const int nxt = cur ^ 1;
    if (kk < 7) {
      const int k1 = (kk + 1) * 32 + quad * 8;
#pragma unroll
      for (int mi = 0; mi < 4; ++mi) {
        const int m = m0 + wm + mi * 16 + l15;
        a[nxt][mi] = *(const bfrag_t*)&xb[(size_t)m * NF + k1];
      }
#pragma unroll
      for (int ni = 0; ni < 4; ++ni) {
        const int n = wn + ni * 16 + l15;
        bb[nxt][ni] = *(const bfrag_t*)&Wk[(size_t)n * NF + k1];
      }
    }
#pragma unroll
    for (int mi = 0; mi < 4; ++mi)
#pragma unroll
      for (int ni = 0; ni < 4; ++ni)
        acc[mi][ni] = __builtin_amdgcn_mfma_f32_16x16x32_bf16(
            a[cur][mi], bb[cur][ni], acc[mi][ni], 0, 0, 0);
  }

#pragma unroll
  for (int ni = 0; ni < 4; ++ni) {
    const int n = wn + ni * 16 + l15;
    const float bias = bk[n];
#pragma unroll
    for (int mi = 0; mi < 4; ++mi) {
#pragma unroll
      for (int r = 0; r < 4; ++r) {
        const int m = m0 + wm + mi * 16 + quad * 4 + r;
        if (m < NNODES) hb[(size_t)m * NH + n] = f2bf(acc[mi][ni][r] + bias);
      }
    }
  }
}

// ---------------------------------------------------------------------------
// CSR scatter (proven R2/R4 form): 1 edge/thread, per-row cursor atomics
// (~16/address), packed (col,val) 8B nontemporal store. ~200us = random-8B
// sector floor (3.2M x 64B); bucket alternatives lose to the ~800cyc
// same-address atomic serialization (R8).
// ---------------------------------------------------------------------------
__global__ __launch_bounds__(256) void scatter_kernel(
    const int* __restrict__ erows, const int* __restrict__ ecols,
    const float* __restrict__ evals, int* __restrict__ cursor,
    ull_t* __restrict__ ecsr) {
  const int hop = blockIdx.y;
  const int e = blockIdx.x * 256 + threadIdx.x;
  const size_t g = (size_t)hop * NEDGES + e;
  const int r = erows[g];
  const int pos = atomicAdd(&cursor[hop * NNODES + r], 1);
  const ull_t pk =
      ((ull_t)__float_as_uint(evals[g]) << 32) | (unsigned int)ecols[g];
  __builtin_nontemporal_store(pk, &ecsr[(size_t)hop * NEDGES + pos]);
}

// ---------------------------------------------------------------------------
// Fused gather+out: block = 16 nodes. Wave w gathers its 16 rows for hop w
// (4 edge-groups x 16 lanes x 16B, 16 edges in flight), applies ELU, writes
// bf16 zs[node][w*128..]. Then all 4 waves do the 512->64 GEMM. No agg
// buffer, no inter-hop race, one dispatch.
// ---------------------------------------------------------------------------
__global__ __launch_bounds__(256) void gatherout_kernel(
    const int* __restrict__ offs_all, const ull_t* __restrict__ ecsr_all,
    const unsigned short* __restrict__ slots, const float* __restrict__ Wout,
    const float* __restrict__ bout, float* __restrict__ out) {
  __shared__ unsigned short zs[16 * ZSTR];
  const int t    = threadIdx.x;
  const int lane = t & 63;
  const int w    = t >> 6;          // wave = hop
  const int n0   = blockIdx.x * 16;
  const int g    = lane >> 4;       // edge subgroup 0..3
  const int sl   = lane & 15;       // feature slice: feats sl*8..sl*8+7

  const int* offs = offs_all + (size_t)w * (NNODES + 1);
  const int2* ecsr = (const int2*)(ecsr_all + (size_t)w * NEDGES);
  const unsigned short* hb = slots + (size_t)w * NNODES * NH;

  for (int nn = 0; nn < 16; ++nn) {
    const int r = n0 + nn;
    const int s = offs[r];
    const int e = offs[r + 1];

    float acc[8];
#pragma unroll
    for (int j = 0; j < 8; ++j) acc[j] = 0.f;

    for (int p = s; p < e; p += 16) {
      int2 ed[4];
#pragma unroll
      for (int q = 0; q < 4; ++q) {
        const int idx = p + q * 4 + g;
        ed[q] = (idx < e) ? ecsr[idx] : make_int2(0, 0);
      }
      uint4 hv[4];
#pragma unroll
      for (int q = 0; q < 4; ++q)
        hv[q] = *(const uint4*)&hb[(size_t)ed[q].x * NH + sl * 8];
#pragma unroll
      for (int q = 0; q < 4; ++q) {
        const float v = __int_as_float(ed[q].y);
        acc[0] += v * bf2f_lo(hv[q].x);
        acc[1] += v * bf2f_hi(hv[q].x);
        acc[2] += v * bf2f_lo(hv[q].y);
        acc[3] += v * bf2f_hi(hv[q].y);
        acc[4] += v * bf2f_lo(hv[q].z);
        acc[5] += v * bf2f_hi(hv[q].z);
        acc[6] += v * bf2f_lo(hv[q].w);
        acc[7] += v * bf2f_hi(hv[q].w);
      }
    }

#pragma unroll
    for (int j = 0; j < 8; ++j) {
      acc[j] += __shfl_xor(acc[j], 16, 64);
      acc[j] += __shfl_xor(acc[j], 32, 64);
    }

    if (g == 0) {
      uint4 o;
      o.x = (unsigned)f2bf(elu(acc[0])) | ((unsigned)f2bf(elu(acc[1])) << 16);
      o.y = (unsigned)f2bf(elu(acc[2])) | ((unsigned)f2bf(elu(acc[3])) << 16);
      o.z = (unsigned)f2bf(elu(acc[4])) | ((unsigned)f2bf(elu(acc[5])) << 16);
      o.w = (unsigned)f2bf(elu(acc[6])) | ((unsigned)f2bf(elu(acc[7])) << 16);
      *(uint4*)&zs[nn * ZSTR + w * NH + sl * 8] = o;
    }
  }
  __syncthreads();

  // ---- GEMM: wave w handles nodes w*4..w*4+3; lane = (og, nloc) ----
  const int og   = lane & 15;       // out cols og*4..og*4+3
  const int nloc = lane >> 4;       // node within wave's group
  const int nn2  = w * 4 + nloc;

  float acc4[4] = {0.f, 0.f, 0.f, 0.f};
  for (int f = 0; f < NHOPS * NH; f += 8) {
    const uint4 zz = *(const uint4*)&zs[nn2 * ZSTR + f];
    const float z[8] = {bf2f_lo(zz.x), bf2f_hi(zz.x), bf2f_lo(zz.y),
                        bf2f_hi(zz.y), bf2f_lo(zz.z), bf2f_hi(zz.z),
                        bf2f_lo(zz.w), bf2f_hi(zz.w)};
#pragma unroll
    for (int u = 0; u < 8; ++u) {
      const float4 wv = *(const float4*)&Wout[(size_t)(f + u) * NO + og * 4];
      acc4[0] += z[u] * wv.x;
      acc4[1] += z[u] * wv.y;
      acc4[2] += z[u] * wv.z;
      acc4[3] += z[u] * wv.w;
    }
  }

  const float4 bo = *(const float4*)&bout[og * 4];
  float4 res = make_float4(acc4[0] + bo.x, acc4[1] + bo.y,
                           acc4[2] + bo.z, acc4[3] + bo.w);
  *(float4*)&out[(size_t)(n0 + nn2) * NO + og * 4] = res;
}

// ---------------------------------------------------------------------------
extern "C" void kernel_launch(void* const* d_in, const int* in_sizes, int n_in,
                              void* d_out, int out_size, void* d_ws, size_t ws_size,
                              hipStream_t stream) {
  const float* x     = (const float*)d_in[0];
  const float* W     = (const float*)d_in[1];
  const float* b     = (const float*)d_in[2];
  const float* W_out = (const float*)d_in[3];
  const float* b_out = (const float*)d_in[4];
  const int*   erows = (const int*)d_in[5];
  const int*   ecols = (const int*)d_in[6];
  const float* evals = (const float*)d_in[7];
  float* out = (float*)d_out;

  // ws layout (bytes), total ~105.2e6 (<118e6 proven-safe):
  //   slots: 4 x NNODES*NH bf16 = 51.2e6  (hb[k] only; agg eliminated)
  //   xb: NPAD*NF bf16 = 25.69e6 | Wt: 0.26e6 | ecsr: 25.6e6 | ints 2.4e6
  unsigned short* slots = (unsigned short*)d_ws;
  unsigned short* xb = slots + (size_t)NHOPS * NNODES * NH;
  unsigned short* Wt = xb + (size_t)NPAD * NF;
  ull_t* ecsr = (ull_t*)(Wt + (size_t)NHOPS * NH * NF);
  int* counts = (int*)(ecsr + (size_t)NHOPS * NEDGES);
  int* offs   = counts + NHOPS * NNODES;
  int* cursor = offs + NHOPS * (NNODES + 1);

  hipMemsetAsync(counts, 0, (size_t)NHOPS * NNODES * sizeof(int), stream);

  phaseA_kernel<<<CONVX_BLOCKS + CONVW_BLOCKS + HIST_BLOCKS, 256, 0, stream>>>(
      x, xb, W, Wt, erows, counts);
  scan_kernel<<<NHOPS, 1024, 0, stream>>>(counts, offs, cursor);
  linear_kernel<<<LIN_BLOCKS, 256, 0, stream>>>(xb, Wt, b, slots);
  scatter_kernel<<<dim3(3125, NHOPS), 256, 0, stream>>>(
      erows, ecols, evals, cursor, ecsr);
  gatherout_kernel<<<NNODES / 16, 256, 0, stream>>>(
      offs, ecsr, slots, W_out, b_out, out);
}